// Round 1
// baseline (162.540 us; speedup 1.0000x reference)
//
#include <hip/hip_runtime.h>
#include <math.h>

#define T_   2048
#define NB_  64
#define NU_  8
#define NY_  8
#define NH_  256
#define H2_  128
#define CCH  32      // number of chunks
#define LCH  64      // chunk length, T_/CCH

#define CBUF_FLOATS (CCH*NB_*H2_*2)   // [k][b][h2][2]
static const float PI_HALF = 1.5707963267948966f;

// ---------------- kernel 1: local chunk scan (zero init) ----------------
__global__ __launch_bounds__(64) void k_local(
    const float* __restrict__ U, const float* __restrict__ lr,
    const float* __restrict__ li, const float* __restrict__ B,
    const float* __restrict__ mult, float* __restrict__ c_buf)
{
    const int k = blockIdx.x / NB_;
    const int b = blockIdx.x % NB_;
    const int j = threadIdx.x;          // 0..63
    const int pa = 2*j, pb = 2*j+1;     // two channel pairs per thread

    // lambda per pair
    float ra  = expf(-fabsf(lr[pa]));
    float tha = PI_HALF * li[pa];
    float rea = ra * cosf(tha), ima = ra * sinf(tha);
    float rb  = expf(-fabsf(lr[pb]));
    float thb = PI_HALF * li[pb];
    float reb = rb * cosf(thb), imb = rb * sinf(thb);

    // B rows scaled by exp(mult)
    float Ba1[NU_], Ba2[NU_], Bb1[NU_], Bb2[NU_];
    {
        float s1 = expf(mult[pa]),      s2 = expf(mult[pa+H2_]);
        float s3 = expf(mult[pb]),      s4 = expf(mult[pb+H2_]);
        #pragma unroll
        for (int i = 0; i < NU_; i++) {
            Ba1[i] = B[pa*NU_ + i]        * s1;
            Ba2[i] = B[(pa+H2_)*NU_ + i]  * s2;
            Bb1[i] = B[pb*NU_ + i]        * s3;
            Bb2[i] = B[(pb+H2_)*NU_ + i]  * s4;
        }
    }

    // stage U chunk for this batch into LDS: [LCH][NU_]
    __shared__ float uS[LCH*NU_];
    {
        const float* src = U + ((size_t)(k*LCH + j)*NB_ + b)*NU_;
        float4 u0 = ((const float4*)src)[0];
        float4 u1 = ((const float4*)src)[1];
        ((float4*)uS)[2*j+0] = u0;
        ((float4*)uS)[2*j+1] = u1;
    }
    __syncthreads();

    float xar = 0.f, xai = 0.f, xbr = 0.f, xbi = 0.f;
    for (int t = 0; t < LCH; t++) {
        float4 u0 = ((const float4*)uS)[2*t+0];
        float4 u1 = ((const float4*)uS)[2*t+1];
        float u[NU_] = {u0.x,u0.y,u0.z,u0.w,u1.x,u1.y,u1.z,u1.w};
        float bua1=0.f, bua2=0.f, bub1=0.f, bub2=0.f;
        #pragma unroll
        for (int i = 0; i < NU_; i++) {
            bua1 = fmaf(u[i], Ba1[i], bua1);
            bua2 = fmaf(u[i], Ba2[i], bua2);
            bub1 = fmaf(u[i], Bb1[i], bub1);
            bub2 = fmaf(u[i], Bb2[i], bub2);
        }
        float nar = fmaf(rea, xar, fmaf(-ima, xai, bua1));
        float nai = fmaf(ima, xar, fmaf( rea, xai, bua2));
        float nbr = fmaf(reb, xbr, fmaf(-imb, xbi, bub1));
        float nbi = fmaf(imb, xbr, fmaf( reb, xbi, bub2));
        xar = nar; xai = nai; xbr = nbr; xbi = nbi;
    }

    float4 cv; cv.x = xar; cv.y = xai; cv.z = xbr; cv.w = xbi;
    float* dst = c_buf + ((size_t)(k*NB_ + b)*(H2_*2)) + 4*j;
    ((float4*)dst)[0] = cv;
}

// ---------------- kernel 2: chunk prefix combine ----------------
__global__ __launch_bounds__(256) void k_prefix(
    const float* __restrict__ y0, const float* __restrict__ lr,
    const float* __restrict__ li, const float* __restrict__ Wy2x,
    const float* __restrict__ by2x, const float* __restrict__ c_buf,
    float* __restrict__ init_buf)
{
    const int g = blockIdx.x*256 + threadIdx.x;   // 0..8191
    const int b = g >> 7;
    const int h = g & 127;

    // x0 = y0 @ Wy2x^T + by2x  (pair h, h+128)
    float x1 = by2x[h], x2 = by2x[h+H2_];
    #pragma unroll
    for (int y = 0; y < NY_; y++) {
        float yy = y0[b*NY_ + y];
        x1 = fmaf(yy, Wy2x[h*NY_ + y],        x1);
        x2 = fmaf(yy, Wy2x[(h+H2_)*NY_ + y],  x2);
    }

    // lambda^L closed form
    float a   = fabsf(lr[h]);
    float rL  = expf(-(float)LCH * a);
    float thL = (float)LCH * PI_HALF * li[h];
    float reL = rL * cosf(thL), imL = rL * sinf(thL);

    for (int k = 0; k < CCH; k++) {
        size_t base = ((size_t)k*NB_ + b)*(H2_*2) + 2*h;
        ((float2*)(init_buf + base))[0] = make_float2(x1, x2);
        float2 c = ((const float2*)(c_buf + base))[0];
        float n1 = fmaf(reL, x1, fmaf(-imL, x2, c.x));
        float n2 = fmaf(imL, x1, fmaf( reL, x2, c.y));
        x1 = n1; x2 = n2;
    }
}

// ---------------- kernel 3: replay with true init + emit Y ----------------
__global__ __launch_bounds__(64) void k_emit(
    const float* __restrict__ U, const float* __restrict__ lr,
    const float* __restrict__ li, const float* __restrict__ B,
    const float* __restrict__ mult, const float* __restrict__ Wx2y,
    const float* __restrict__ bx2y, const float* __restrict__ init_buf,
    float* __restrict__ Y)
{
    const int k = blockIdx.x / NB_;
    const int b = blockIdx.x % NB_;
    const int j = threadIdx.x;
    const int pa = 2*j, pb = 2*j+1;

    float ra  = expf(-fabsf(lr[pa]));
    float tha = PI_HALF * li[pa];
    float rea = ra * cosf(tha), ima = ra * sinf(tha);
    float rb  = expf(-fabsf(lr[pb]));
    float thb = PI_HALF * li[pb];
    float reb = rb * cosf(thb), imb = rb * sinf(thb);

    float Ba1[NU_], Ba2[NU_], Bb1[NU_], Bb2[NU_];
    {
        float s1 = expf(mult[pa]),      s2 = expf(mult[pa+H2_]);
        float s3 = expf(mult[pb]),      s4 = expf(mult[pb+H2_]);
        #pragma unroll
        for (int i = 0; i < NU_; i++) {
            Ba1[i] = B[pa*NU_ + i]        * s1;
            Ba2[i] = B[(pa+H2_)*NU_ + i]  * s2;
            Bb1[i] = B[pb*NU_ + i]        * s3;
            Bb2[i] = B[(pb+H2_)*NU_ + i]  * s4;
        }
    }

    // output projection coefficients for this thread's 4 state components
    float wa1[NY_], wa2[NY_], wb1[NY_], wb2[NY_], bias[NY_];
    #pragma unroll
    for (int y = 0; y < NY_; y++) {
        wa1[y] = Wx2y[y*NH_ + pa];
        wa2[y] = Wx2y[y*NH_ + pa + H2_];
        wb1[y] = Wx2y[y*NH_ + pb];
        wb2[y] = Wx2y[y*NH_ + pb + H2_];
        bias[y] = bx2y[y];
    }

    __shared__ float uS[LCH*NU_];
    {
        const float* src = U + ((size_t)(k*LCH + j)*NB_ + b)*NU_;
        float4 u0 = ((const float4*)src)[0];
        float4 u1 = ((const float4*)src)[1];
        ((float4*)uS)[2*j+0] = u0;
        ((float4*)uS)[2*j+1] = u1;
    }
    __syncthreads();

    float4 ini = ((const float4*)(init_buf + ((size_t)(k*NB_ + b)*(H2_*2))))[j];
    float xar = ini.x, xai = ini.y, xbr = ini.z, xbi = ini.w;

    float* outbase = Y + ((size_t)k*LCH*NB_ + b)*NY_;

    for (int t = 0; t < LCH; t++) {
        float4 u0 = ((const float4*)uS)[2*t+0];
        float4 u1 = ((const float4*)uS)[2*t+1];
        float u[NU_] = {u0.x,u0.y,u0.z,u0.w,u1.x,u1.y,u1.z,u1.w};
        float bua1=0.f, bua2=0.f, bub1=0.f, bub2=0.f;
        #pragma unroll
        for (int i = 0; i < NU_; i++) {
            bua1 = fmaf(u[i], Ba1[i], bua1);
            bua2 = fmaf(u[i], Ba2[i], bua2);
            bub1 = fmaf(u[i], Bb1[i], bub1);
            bub2 = fmaf(u[i], Bb2[i], bub2);
        }
        float nar = fmaf(rea, xar, fmaf(-ima, xai, bua1));
        float nai = fmaf(ima, xar, fmaf( rea, xai, bua2));
        float nbr = fmaf(reb, xbr, fmaf(-imb, xbi, bub1));
        float nbi = fmaf(imb, xbr, fmaf( reb, xbi, bub2));
        xar = nar; xai = nai; xbr = nbr; xbi = nbi;

        float p[NY_];
        #pragma unroll
        for (int y = 0; y < NY_; y++) {
            p[y] = fmaf(xar, wa1[y], fmaf(xai, wa2[y],
                   fmaf(xbr, wb1[y], xbi * wb2[y])));
        }
        // full-wave butterfly reduction (all lanes end with the sums)
        #pragma unroll
        for (int m = 32; m >= 1; m >>= 1) {
            #pragma unroll
            for (int y = 0; y < NY_; y++)
                p[y] += __shfl_xor(p[y], m, 64);
        }
        if (j == 0) {
            float4 o0, o1;
            o0.x = p[0]+bias[0]; o0.y = p[1]+bias[1];
            o0.z = p[2]+bias[2]; o0.w = p[3]+bias[3];
            o1.x = p[4]+bias[4]; o1.y = p[5]+bias[5];
            o1.z = p[6]+bias[6]; o1.w = p[7]+bias[7];
            float* o = outbase + (size_t)t*NB_*NY_;
            ((float4*)o)[0] = o0;
            ((float4*)o)[1] = o1;
        }
    }
}

extern "C" void kernel_launch(void* const* d_in, const int* in_sizes, int n_in,
                              void* d_out, int out_size, void* d_ws, size_t ws_size,
                              hipStream_t stream) {
    const float* y0   = (const float*)d_in[0];
    const float* U    = (const float*)d_in[1];
    const float* lr   = (const float*)d_in[2];
    const float* li   = (const float*)d_in[3];
    const float* B    = (const float*)d_in[4];
    const float* mult = (const float*)d_in[5];
    const float* Wy2x = (const float*)d_in[6];
    const float* by2x = (const float*)d_in[7];
    const float* Wx2y = (const float*)d_in[8];
    const float* bx2y = (const float*)d_in[9];
    float* Y = (float*)d_out;

    float* c_buf    = (float*)d_ws;
    float* init_buf = c_buf + CBUF_FLOATS;

    k_local <<<CCH*NB_, 64,  0, stream>>>(U, lr, li, B, mult, c_buf);
    k_prefix<<<(NB_*H2_)/256, 256, 0, stream>>>(y0, lr, li, Wy2x, by2x, c_buf, init_buf);
    k_emit  <<<CCH*NB_, 64,  0, stream>>>(U, lr, li, B, mult, Wx2y, bx2y, init_buf, Y);
}

// Round 2
// 112.052 us; speedup vs baseline: 1.4506x; 1.4506x over previous
//
#include <hip/hip_runtime.h>
#include <math.h>

#define T_   2048
#define NB_  64
#define NU_  8
#define NY_  8
#define NH_  256
#define H2_  128
#define CCH  64      // number of chunks
#define LCH  32      // chunk length = T_/CCH
#define TT_  4       // time tile in k_emit

static const float PI_HALF = 1.5707963267948966f;

// Lane j owns channels {j, j+64} as pairs: pair p has components (x[p], x[p+128]).
// So lane j tracks channels j, j+128 (pair j) and j+64, j+192 (pair j+64).

// ---------------- kernel 1: local chunk scan (zero init) ----------------
__global__ __launch_bounds__(64) void k_local(
    const float* __restrict__ U, const float* __restrict__ lr,
    const float* __restrict__ li, const float* __restrict__ B,
    const float* __restrict__ mult, float* __restrict__ buf)
{
    const int k = blockIdx.x >> 6;
    const int b = blockIdx.x & 63;
    const int j = threadIdx.x;
    const int p1 = j, p2 = j + 64;

    float r1  = expf(-fabsf(lr[p1]));
    float t1  = PI_HALF * li[p1];
    float re1 = r1 * cosf(t1), im1 = r1 * sinf(t1);
    float r2  = expf(-fabsf(lr[p2]));
    float t2  = PI_HALF * li[p2];
    float re2 = r2 * cosf(t2), im2 = r2 * sinf(t2);

    // B rows for channels j, j+128, j+64, j+192, scaled by exp(mult)
    float B1[NU_], B2[NU_], B3[NU_], B4[NU_];
    {
        float s1 = expf(mult[j]),      s2 = expf(mult[j+128]);
        float s3 = expf(mult[j+64]),   s4 = expf(mult[j+192]);
        #pragma unroll
        for (int i = 0; i < NU_; i++) {
            B1[i] = B[(j      )*NU_ + i] * s1;
            B2[i] = B[(j + 128)*NU_ + i] * s2;
            B3[i] = B[(j +  64)*NU_ + i] * s3;
            B4[i] = B[(j + 192)*NU_ + i] * s4;
        }
    }

    __shared__ float uS[LCH*NU_];   // [32][8]
    {
        int t = j >> 1, half = j & 1;
        float4 v = *(const float4*)(U + ((size_t)(k*LCH + t)*NB_ + b)*NU_ + half*4);
        ((float4*)uS)[j] = v;
    }
    __syncthreads();

    float x1a=0.f, x2a=0.f, x1b=0.f, x2b=0.f;
    #pragma unroll 8
    for (int t = 0; t < LCH; t++) {
        float4 u0 = ((const float4*)uS)[2*t+0];
        float4 u1 = ((const float4*)uS)[2*t+1];
        float u[NU_] = {u0.x,u0.y,u0.z,u0.w,u1.x,u1.y,u1.z,u1.w};
        float bu1=0.f, bu2=0.f, bu3=0.f, bu4=0.f;
        #pragma unroll
        for (int i = 0; i < NU_; i++) {
            bu1 = fmaf(u[i], B1[i], bu1);
            bu2 = fmaf(u[i], B2[i], bu2);
            bu3 = fmaf(u[i], B3[i], bu3);
            bu4 = fmaf(u[i], B4[i], bu4);
        }
        float n1a = fmaf(re1, x1a, fmaf(-im1, x2a, bu1));
        float n2a = fmaf(im1, x1a, fmaf( re1, x2a, bu2));
        float n1b = fmaf(re2, x1b, fmaf(-im2, x2b, bu3));
        float n2b = fmaf(im2, x1b, fmaf( re2, x2b, bu4));
        x1a=n1a; x2a=n2a; x1b=n1b; x2b=n2b;
    }

    float* base = buf + ((size_t)(k*NB_ + b))*(H2_*2);
    *(float2*)(base + 2*j)       = make_float2(x1a, x2a);
    *(float2*)(base + 128 + 2*j) = make_float2(x1b, x2b);
}

// ---------------- kernel 2: chunk prefix combine (in-place: endpoint -> init) ---
__global__ __launch_bounds__(256) void k_prefix(
    const float* __restrict__ y0, const float* __restrict__ lr,
    const float* __restrict__ li, const float* __restrict__ Wy2x,
    const float* __restrict__ by2x, float* __restrict__ buf)
{
    const int g = blockIdx.x*256 + threadIdx.x;   // 0..8191
    const int b = g >> 7;
    const int h = g & 127;

    float x1 = by2x[h], x2 = by2x[h+H2_];
    #pragma unroll
    for (int y = 0; y < NY_; y++) {
        float yy = y0[b*NY_ + y];
        x1 = fmaf(yy, Wy2x[h*NY_ + y],        x1);
        x2 = fmaf(yy, Wy2x[(h+H2_)*NY_ + y],  x2);
    }

    float rL  = expf(-(float)LCH * fabsf(lr[h]));
    float thL = (float)LCH * PI_HALF * li[h];
    float reL = rL * cosf(thL), imL = rL * sinf(thL);

    #pragma unroll 8
    for (int k = 0; k < CCH; k++) {
        float* p = buf + ((size_t)(k*NB_ + b))*(H2_*2) + 2*h;
        float2 c = *(const float2*)p;          // read endpoint first
        *(float2*)p = make_float2(x1, x2);     // then overwrite with init
        float n1 = fmaf(reL, x1, fmaf(-imL, x2, c.x));
        float n2 = fmaf(imL, x1, fmaf( reL, x2, c.y));
        x1 = n1; x2 = n2;
    }
}

// ---------------- kernel 3: replay with true init + tiled projection ----------
__global__ __launch_bounds__(64) void k_emit(
    const float* __restrict__ U, const float* __restrict__ lr,
    const float* __restrict__ li, const float* __restrict__ B,
    const float* __restrict__ mult, const float* __restrict__ Wx2y,
    const float* __restrict__ bx2y, const float* __restrict__ buf,
    float* __restrict__ Y)
{
    const int k = blockIdx.x >> 6;
    const int b = blockIdx.x & 63;
    const int j = threadIdx.x;
    const int p1 = j, p2 = j + 64;

    float r1  = expf(-fabsf(lr[p1]));
    float t1  = PI_HALF * li[p1];
    float re1 = r1 * cosf(t1), im1 = r1 * sinf(t1);
    float r2  = expf(-fabsf(lr[p2]));
    float t2  = PI_HALF * li[p2];
    float re2 = r2 * cosf(t2), im2 = r2 * sinf(t2);

    float B1[NU_], B2[NU_], B3[NU_], B4[NU_];
    {
        float s1 = expf(mult[j]),      s2 = expf(mult[j+128]);
        float s3 = expf(mult[j+64]),   s4 = expf(mult[j+192]);
        #pragma unroll
        for (int i = 0; i < NU_; i++) {
            B1[i] = B[(j      )*NU_ + i] * s1;
            B2[i] = B[(j + 128)*NU_ + i] * s2;
            B3[i] = B[(j +  64)*NU_ + i] * s3;
            B4[i] = B[(j + 192)*NU_ + i] * s4;
        }
    }

    // W columns for this lane's 4 channels (coalesced: consecutive lanes,
    // consecutive addresses)
    float W1[NY_], W2[NY_], W3[NY_], W4[NY_];
    #pragma unroll
    for (int y = 0; y < NY_; y++) {
        W1[y] = Wx2y[y*NH_ + j      ];
        W2[y] = Wx2y[y*NH_ + j + 128];
        W3[y] = Wx2y[y*NH_ + j +  64];
        W4[y] = Wx2y[y*NH_ + j + 192];
    }
    const float biasv = bx2y[j & 7];

    __shared__ float uS[LCH*NU_];
    __shared__ float pS[64*36];    // [lane][32 partials], stride 36 (bank-spread)
    {
        int t = j >> 1, half = j & 1;
        float4 v = *(const float4*)(U + ((size_t)(k*LCH + t)*NB_ + b)*NU_ + half*4);
        ((float4*)uS)[j] = v;
    }

    const float* base = buf + ((size_t)(k*NB_ + b))*(H2_*2);
    float2 i1 = *(const float2*)(base + 2*j);
    float2 i2 = *(const float2*)(base + 128 + 2*j);
    float x1a=i1.x, x2a=i1.y, x1b=i2.x, x2b=i2.y;
    __syncthreads();

    float* outk = Y + ((size_t)k*LCH*NB_ + b)*NY_;

    for (int tt = 0; tt < LCH/TT_; tt++) {
        float p[TT_*NY_];
        #pragma unroll
        for (int t4 = 0; t4 < TT_; t4++) {
            int t = tt*TT_ + t4;
            float4 u0 = ((const float4*)uS)[2*t+0];
            float4 u1 = ((const float4*)uS)[2*t+1];
            float u[NU_] = {u0.x,u0.y,u0.z,u0.w,u1.x,u1.y,u1.z,u1.w};
            float bu1=0.f, bu2=0.f, bu3=0.f, bu4=0.f;
            #pragma unroll
            for (int i = 0; i < NU_; i++) {
                bu1 = fmaf(u[i], B1[i], bu1);
                bu2 = fmaf(u[i], B2[i], bu2);
                bu3 = fmaf(u[i], B3[i], bu3);
                bu4 = fmaf(u[i], B4[i], bu4);
            }
            float n1a = fmaf(re1, x1a, fmaf(-im1, x2a, bu1));
            float n2a = fmaf(im1, x1a, fmaf( re1, x2a, bu2));
            float n1b = fmaf(re2, x1b, fmaf(-im2, x2b, bu3));
            float n2b = fmaf(im2, x1b, fmaf( re2, x2b, bu4));
            x1a=n1a; x2a=n2a; x1b=n1b; x2b=n2b;

            #pragma unroll
            for (int y = 0; y < NY_; y++) {
                p[t4*NY_ + y] = fmaf(x1a, W1[y], fmaf(x2a, W2[y],
                                fmaf(x1b, W3[y], x2b * W4[y])));
            }
        }
        // bulk transpose-reduce through LDS
        float* row = pS + j*36;
        #pragma unroll
        for (int g = 0; g < 8; g++) {
            *(float4*)(row + 4*g) =
                make_float4(p[4*g+0], p[4*g+1], p[4*g+2], p[4*g+3]);
        }
        __syncthreads();
        {
            const int idx = j & 31;      // (t4, y) column this lane sums
            const int lh  = j >> 5;      // which half of the lanes to sum
            float s0=0.f, s1=0.f, s2=0.f, s3=0.f;
            #pragma unroll
            for (int s = 0; s < 32; s += 4) {
                s0 += pS[(lh*32 + s+0)*36 + idx];
                s1 += pS[(lh*32 + s+1)*36 + idx];
                s2 += pS[(lh*32 + s+2)*36 + idx];
                s3 += pS[(lh*32 + s+3)*36 + idx];
            }
            float sum = (s0+s1) + (s2+s3);
            sum += __shfl_xor(sum, 32, 64);
            if (j < 32) {
                int t4 = j >> 3, y = j & 7;
                outk[(size_t)(tt*TT_ + t4)*NB_*NY_ + y] = sum + biasv;
            }
        }
        __syncthreads();
    }
}

extern "C" void kernel_launch(void* const* d_in, const int* in_sizes, int n_in,
                              void* d_out, int out_size, void* d_ws, size_t ws_size,
                              hipStream_t stream) {
    const float* y0   = (const float*)d_in[0];
    const float* U    = (const float*)d_in[1];
    const float* lr   = (const float*)d_in[2];
    const float* li   = (const float*)d_in[3];
    const float* B    = (const float*)d_in[4];
    const float* mult = (const float*)d_in[5];
    const float* Wy2x = (const float*)d_in[6];
    const float* by2x = (const float*)d_in[7];
    const float* Wx2y = (const float*)d_in[8];
    const float* bx2y = (const float*)d_in[9];
    float* Y = (float*)d_out;

    float* buf = (float*)d_ws;   // CCH*NB*256 floats = 4 MB (endpoints -> inits)

    k_local <<<CCH*NB_, 64,  0, stream>>>(U, lr, li, B, mult, buf);
    k_prefix<<<(NB_*H2_)/256, 256, 0, stream>>>(y0, lr, li, Wy2x, by2x, buf);
    k_emit  <<<CCH*NB_, 64,  0, stream>>>(U, lr, li, B, mult, Wx2y, bx2y, buf, Y);
}